// Round 1
// baseline (128.334 us; speedup 1.0000x reference)
//
#include <hip/hip_runtime.h>
#include <math.h>

#define BATCH 16384
#define CTX 10
#define NEG 5
#define DIM 128
#define B_PER_BLOCK 8
#define NBLOCKS (BATCH / B_PER_BLOCK)   // 2048

// logsigmoid(x) = min(x,0) - log1p(exp(-|x|))   (numerically stable)
__device__ __forceinline__ float logsig(float x) {
    return fminf(x, 0.f) - log1pf(expf(-fabsf(x)));
}

__global__ __launch_bounds__(256) void cbow_partial(
    const int* __restrict__ pos_u,      // [B, CTX]
    const int* __restrict__ pos_w,      // [B]
    const int* __restrict__ neg_w,      // [B, NEG]
    const float* __restrict__ u_weight, // [VOCAB, DIM]
    const float* __restrict__ w_weight, // [VOCAB, DIM]
    float* __restrict__ partials)       // [NBLOCKS]
{
    const int tid   = threadIdx.x;
    const int group = tid >> 5;         // 0..7 : which b within block
    const int lane  = tid & 31;         // 0..31: 4 dims each
    const int b     = blockIdx.x * B_PER_BLOCK + group;
    const int col   = lane * 4;

    // --- sum of CTX context embeddings (this lane's 4 dims) ---
    float4 su = make_float4(0.f, 0.f, 0.f, 0.f);
#pragma unroll
    for (int c = 0; c < CTX; ++c) {
        const int idx = pos_u[b * CTX + c];
        const float4 v = *reinterpret_cast<const float4*>(
            u_weight + (size_t)idx * DIM + col);
        su.x += v.x; su.y += v.y; su.z += v.z; su.w += v.w;
    }

    // --- positive score contribution ---
    const int pw = pos_w[b];
    const float4 wp = *reinterpret_cast<const float4*>(
        w_weight + (size_t)pw * DIM + col);
    float s_pos = su.x * wp.x + su.y * wp.y + su.z * wp.z + su.w * wp.w;

    // --- negatives: sum rows first (reference sums over NEG before logsig) ---
    float4 wn = make_float4(0.f, 0.f, 0.f, 0.f);
#pragma unroll
    for (int k = 0; k < NEG; ++k) {
        const int idx = neg_w[b * NEG + k];
        const float4 v = *reinterpret_cast<const float4*>(
            w_weight + (size_t)idx * DIM + col);
        wn.x += v.x; wn.y += v.y; wn.z += v.z; wn.w += v.w;
    }
    float s_neg = su.x * wn.x + su.y * wn.y + su.z * wn.z + su.w * wn.w;

    // --- reduce dot products across the 32-lane group (xor masks <=16 stay in-group) ---
#pragma unroll
    for (int m = 16; m >= 1; m >>= 1) {
        s_pos += __shfl_xor(s_pos, m, 64);
        s_neg += __shfl_xor(s_neg, m, 64);
    }

    // --- per-block accumulation in LDS, one write per block ---
    __shared__ float part;
    if (tid == 0) part = 0.f;
    __syncthreads();
    if (lane == 0) {
        const float t = logsig(s_pos) + logsig(-s_neg);
        atomicAdd(&part, t);
    }
    __syncthreads();
    if (tid == 0) partials[blockIdx.x] = part;
}

__global__ __launch_bounds__(256) void cbow_reduce(
    const float* __restrict__ partials, // [NBLOCKS]
    float* __restrict__ out)
{
    const int tid = threadIdx.x;
    float s = 0.f;
    for (int i = tid; i < NBLOCKS; i += 256) s += partials[i];
    // wave64 reduction
#pragma unroll
    for (int m = 32; m >= 1; m >>= 1) s += __shfl_xor(s, m, 64);
    __shared__ float ws[4];
    if ((tid & 63) == 0) ws[tid >> 6] = s;
    __syncthreads();
    if (tid == 0) {
        float tot = ws[0] + ws[1] + ws[2] + ws[3];
        out[0] = -tot;   // reference returns -loss
    }
}

extern "C" void kernel_launch(void* const* d_in, const int* in_sizes, int n_in,
                              void* d_out, int out_size, void* d_ws, size_t ws_size,
                              hipStream_t stream) {
    const int*   pos_u    = (const int*)d_in[0];
    const int*   pos_w    = (const int*)d_in[1];
    const int*   neg_w    = (const int*)d_in[2];
    const float* u_weight = (const float*)d_in[3];
    const float* w_weight = (const float*)d_in[4];
    float*       out      = (float*)d_out;
    float*       partials = (float*)d_ws;   // NBLOCKS floats

    cbow_partial<<<NBLOCKS, 256, 0, stream>>>(pos_u, pos_w, neg_w,
                                              u_weight, w_weight, partials);
    cbow_reduce<<<1, 256, 0, stream>>>(partials, out);
}